// Round 4
// baseline (1000.825 us; speedup 1.0000x reference)
//
#include <hip/hip_runtime.h>
#include <hip/hip_bf16.h>

typedef __bf16 bf16x8 __attribute__((ext_vector_type(8)));
typedef float f32x4 __attribute__((ext_vector_type(4)));
typedef unsigned short u16;

__device__ __forceinline__ u16 f2bf(float f) {
  __bf16 b = (__bf16)f;                 // RNE fptrunc
  return __builtin_bit_cast(u16, b);
}

// ---------------- cast X (fp32 -> bf16), 4 elems/thread ----------------
__global__ void cast_f32_bf16_x4(const float* __restrict__ src, u16* __restrict__ dst, int n4) {
  int i = blockIdx.x * blockDim.x + threadIdx.x;
  if (i < n4) {
    float4 f = reinterpret_cast<const float4*>(src)[i];
    ushort4 o;
    o.x = f2bf(f.x); o.y = f2bf(f.y); o.z = f2bf(f.z); o.w = f2bf(f.w);
    reinterpret_cast<ushort4*>(dst)[i] = o;
  }
}

// ---------------- cast 3 weights (fp32 -> bf16, straight) ----------------
struct CPtrs { const float* s[3]; u16* d[3]; };
__global__ void cast3_w(CPtrs p, int n4) {
  int i = blockIdx.x * blockDim.x + threadIdx.x;
  const float* src = p.s[blockIdx.z];
  u16* dst = p.d[blockIdx.z];
  if (i < n4) {
    float4 f = reinterpret_cast<const float4*>(src)[i];
    ushort4 o;
    o.x = f2bf(f.x); o.y = f2bf(f.y); o.z = f2bf(f.z); o.w = f2bf(f.w);
    reinterpret_cast<ushort4*>(dst)[i] = o;
  }
}

// ---------------- transpose+cast weight: W[k][n] fp32 -> Wt[n][k] bf16 ----------------
struct TPtrs { const float* s[3]; u16* d[3]; };

__global__ void transpose_cast_w(TPtrs p) {
  __shared__ float t[32][33];
  const float* src = p.s[blockIdx.z];
  u16* dst = p.d[blockIdx.z];
  int tx = threadIdx.x, ty = threadIdx.y;          // block (32,8)
  int x = blockIdx.x * 32 + tx;
#pragma unroll
  for (int i = 0; i < 4; ++i) {
    int y = blockIdx.y * 32 + ty + i * 8;
    t[ty + i * 8][tx] = src[(size_t)y * 2048 + x];
  }
  __syncthreads();
  int x2 = blockIdx.y * 32 + tx;
#pragma unroll
  for (int i = 0; i < 4; ++i) {
    int y2 = blockIdx.x * 32 + ty + i * 8;
    dst[(size_t)y2 * 2048 + x2] = f2bf(t[tx][ty + i * 8]);
  }
}

// ---------------- per-slab transpose Vm[s][d] -> VT[d][s] (bf16) ----------------
__global__ void transpose_slab(const u16* __restrict__ src, u16* __restrict__ dst) {
  __shared__ u16 t[32][33];
  int slab = blockIdx.z;
  const u16* s = src + (size_t)slab * 2048 * 128;
  u16* d = dst + (size_t)slab * 128 * 2048;
  int tx = threadIdx.x, ty = threadIdx.y;          // block (32,8)
#pragma unroll
  for (int i = 0; i < 4; ++i)
    t[ty + i * 8][tx] = s[(size_t)(blockIdx.x * 32 + ty + i * 8) * 128 + blockIdx.y * 32 + tx];
  __syncthreads();
#pragma unroll
  for (int i = 0; i < 4; ++i)
    d[(size_t)(blockIdx.y * 32 + ty + i * 8) * 2048 + blockIdx.x * 32 + tx] = t[tx][ty + i * 8];
}

// ---------------- bf16 MFMA GEMM: C[M][N] = A[M][K] * Bt[N][K]^T ----------------
struct GemmArgs { const u16* A[3]; const u16* B[3]; void* C[3]; };

template <bool F32OUT>
__global__ __launch_bounds__(256, 2)
void gemm_bt(GemmArgs g, int M, int N, int K) {
  (void)M;
  __shared__ __align__(16) u16 lds[16384];      // 32 KB: A tile then B tile
  u16* As = lds;
  u16* Bs = lds + 8192;
  const u16* A = g.A[blockIdx.z];
  const u16* B = g.B[blockIdx.z];
  const int tid = threadIdx.x;
  const int lane = tid & 63, w = tid >> 6;
  const int l15 = lane & 15, quad = lane >> 4;
  const int wm = w & 1, wn = w >> 1;
  const int m0 = blockIdx.y * 128, n0 = blockIdx.x * 128;

  const f32x4 zf = {0.f, 0.f, 0.f, 0.f};
  f32x4 acc[4][4];
#pragma unroll
  for (int i = 0; i < 4; ++i)
#pragma unroll
    for (int j = 0; j < 4; ++j) acc[i][j] = zf;

  for (int k0 = 0; k0 < K; k0 += 64) {
#pragma unroll
    for (int t = 0; t < 8; ++t) {
      int idx = w * 8 + t;              // 0..31
      int mat = idx >> 4;               // 0 = A, 1 = B
      int sub = idx & 15;
      int kb = sub >> 1, rb = sub & 1;
      const u16* src = mat ? B : A;
      int row = (mat ? n0 : m0) + rb * 64 + lane;
      const u16* gp = src + (size_t)row * K + k0 + kb * 8;
      u16* lp = (mat ? Bs : As) + (kb * 2 + rb) * 64 * 8;
      __builtin_amdgcn_global_load_lds((const __attribute__((address_space(1))) void*)gp,
                                       (__attribute__((address_space(3))) void*)lp,
                                       16, 0, 0);
    }
    __syncthreads();
#pragma unroll
    for (int kc = 0; kc < 2; ++kc) {
      bf16x8 a[4], bb[4];
#pragma unroll
      for (int mt = 0; mt < 4; ++mt)
        a[mt] = *reinterpret_cast<const bf16x8*>(
            As + (((kc * 4 + quad) * 2 + wm) * 64 + mt * 16 + l15) * 8);
#pragma unroll
      for (int nt = 0; nt < 4; ++nt)
        bb[nt] = *reinterpret_cast<const bf16x8*>(
            Bs + (((kc * 4 + quad) * 2 + wn) * 64 + nt * 16 + l15) * 8);
#pragma unroll
      for (int mt = 0; mt < 4; ++mt)
#pragma unroll
        for (int nt = 0; nt < 4; ++nt)
          acc[mt][nt] = __builtin_amdgcn_mfma_f32_16x16x32_bf16(a[mt], bb[nt], acc[mt][nt], 0, 0, 0);
    }
    __syncthreads();
  }

#pragma unroll
  for (int mt = 0; mt < 4; ++mt)
#pragma unroll
    for (int nt = 0; nt < 4; ++nt)
#pragma unroll
      for (int r = 0; r < 4; ++r) {
        int mrow = m0 + wm * 64 + mt * 16 + quad * 4 + r;   // D row = quad*4+reg
        int ncol = n0 + wn * 64 + nt * 16 + l15;            // D col = lane&15
        if constexpr (F32OUT)
          ((float*)g.C[blockIdx.z])[(size_t)mrow * N + ncol] = acc[mt][nt][r];
        else
          ((u16*)g.C[blockIdx.z])[(size_t)mrow * N + ncol] = f2bf(acc[mt][nt][r]);
      }
}

// ---------------- flash attention v3: no-max softmax, KC=64, 32q/wave ----------------
// LDS 40 KB (Ks16 + Vs16 + PL8) -> up to 4 blocks/CU; PV interleaved per m-tile so
// the per-wave P buffer is only 16 rows (DS ops are in-order per wave: the mt=1
// writes cannot pass the mt=0 aP reads).
// grid (16 qblocks, 16 heads, 2 batch), block 256 (4 waves x 32 q-rows = 128 q/block).
__global__ __launch_bounds__(256, 3)
void flash_attn(const u16* __restrict__ Qm, const u16* __restrict__ Km,
                const u16* __restrict__ VTr, const int* __restrict__ mask,
                u16* __restrict__ Out) {
  __shared__ __align__(16) u16 Ks[16 * 64 * 8];   // [dchunk(16)][kk(64)][8]  16 KB
  __shared__ __align__(16) u16 Vs[8 * 128 * 8];   // [kchunk(8)][d(128)][8]   16 KB
  __shared__ __align__(16) u16 PL[4][16 * 64];    // per-wave P 16x64, XOR-swizzled; 8 KB

  const int b = blockIdx.z, head = blockIdx.y, qb = blockIdx.x;
  const int slab = b * 16 + head;
  const u16* Qs = Qm + (size_t)slab * 2048 * 128;
  const u16* Kg = Km + (size_t)slab * 2048 * 128;
  const u16* Vg = VTr + (size_t)slab * 128 * 2048;
  u16* Og = Out + (size_t)slab * 2048 * 128;
  const int* mb = mask + b * 2048;

  const int tid = threadIdx.x;
  const int lane = tid & 63, w = tid >> 6;
  const int l15 = lane & 15, quad = lane >> 4;
  const int q0w = qb * 128 + w * 32;

  // Q fragments for 2 m-tiles: A[m=lane&15][k=quad*8+j]
  bf16x8 aQ[2][4];
#pragma unroll
  for (int mt = 0; mt < 2; ++mt)
#pragma unroll
    for (int c = 0; c < 4; ++c)
      aQ[mt][c] = *reinterpret_cast<const bf16x8*>(
          Qs + (size_t)(q0w + mt * 16 + l15) * 128 + c * 32 + quad * 8);

  int mq[2][4];
#pragma unroll
  for (int mt = 0; mt < 2; ++mt)
#pragma unroll
    for (int r = 0; r < 4; ++r) mq[mt][r] = mb[q0w + mt * 16 + quad * 4 + r];

  const f32x4 zf = {0.f, 0.f, 0.f, 0.f};
  float l_part[2][4];
  f32x4 acc[2][8];
#pragma unroll
  for (int mt = 0; mt < 2; ++mt) {
#pragma unroll
    for (int r = 0; r < 4; ++r) l_part[mt][r] = 0.f;
#pragma unroll
    for (int nd = 0; nd < 8; ++nd) acc[mt][nd] = zf;
  }

  u16* PLw = PL[w];

  for (int k0 = 0; k0 < 2048; k0 += 64) {
    // stage K chunk [64 kk][128 d] and VT chunk [128 d][64 kk] via direct-to-LDS
#pragma unroll
    for (int t = 0; t < 8; ++t) {
      int idx = w * 8 + t;              // 0..31
      if (idx < 16) {                   // K: dchunk = idx
        const u16* gp = Kg + (size_t)(k0 + lane) * 128 + idx * 8;
        u16* lp = Ks + idx * 64 * 8;
        __builtin_amdgcn_global_load_lds((const __attribute__((address_space(1))) void*)gp,
                                         (__attribute__((address_space(3))) void*)lp,
                                         16, 0, 0);
      } else {                          // V: kchunk = (idx-16)>>1, d-half = (idx-16)&1
        int u = idx - 16, kc = u >> 1, dh = u & 1;
        const u16* gp = Vg + (size_t)(dh * 64 + lane) * 2048 + k0 + kc * 8;
        u16* lp = Vs + (kc * 128 + dh * 64) * 8;
        __builtin_amdgcn_global_load_lds((const __attribute__((address_space(1))) void*)gp,
                                         (__attribute__((address_space(3))) void*)lp,
                                         16, 0, 0);
      }
    }
    __syncthreads();

    // S[32q x 64k] = Q . K^T  (both m-tiles share each bK read)
    f32x4 st[2][4];
#pragma unroll
    for (int mt = 0; mt < 2; ++mt)
#pragma unroll
      for (int nt = 0; nt < 4; ++nt) st[mt][nt] = zf;
#pragma unroll
    for (int c = 0; c < 4; ++c)
#pragma unroll
      for (int nt = 0; nt < 4; ++nt) {
        bf16x8 bK = *reinterpret_cast<const bf16x8*>(
            &Ks[((c * 4 + quad) * 64 + nt * 16 + l15) * 8]);
        st[0][nt] = __builtin_amdgcn_mfma_f32_16x16x32_bf16(aQ[0][c], bK, st[0][nt], 0, 0, 0);
        st[1][nt] = __builtin_amdgcn_mfma_f32_16x16x32_bf16(aQ[1][c], bK, st[1][nt], 0, 0, 0);
      }

    // k-mask from global (L1-cached)
    int mki[4];
#pragma unroll
    for (int nt = 0; nt < 4; ++nt) mki[nt] = mb[k0 + nt * 16 + l15];

    // per m-tile: no-max softmax p = mq ? (mk ? exp(s) : 0) : 1, then PV
#pragma unroll
    for (int mt = 0; mt < 2; ++mt) {
#pragma unroll
      for (int nt = 0; nt < 4; ++nt)
#pragma unroll
        for (int r = 0; r < 4; ++r) {
          float e = __expf(st[mt][nt][r]);
          float p = mq[mt][r] ? (mki[nt] ? e : 0.0f) : 1.0f;
          l_part[mt][r] += p;
          int row = quad * 4 + r;                      // D row = quad*4+reg
          int chunk = (nt * 2 + (l15 >> 3)) ^ (row & 7);
          PLw[row * 64 + (chunk << 3) + (l15 & 7)] = f2bf(p);
        }
#pragma unroll
      for (int pc = 0; pc < 2; ++pc) {
        bf16x8 aP = *reinterpret_cast<const bf16x8*>(
            &PLw[l15 * 64 + (((pc * 4 + quad) ^ (l15 & 7)) << 3)]);
#pragma unroll
        for (int nd = 0; nd < 8; ++nd) {
          bf16x8 bV = *reinterpret_cast<const bf16x8*>(
              &Vs[((pc * 4 + quad) * 128 + nd * 16 + l15) * 8]);
          acc[mt][nd] = __builtin_amdgcn_mfma_f32_16x16x32_bf16(aP, bV, acc[mt][nd], 0, 0, 0);
        }
      }
    }
    __syncthreads();
  }

  // final row-sum reduce over lane&15 (once), then normalize + store
  float inv[2][4];
#pragma unroll
  for (int mt = 0; mt < 2; ++mt)
#pragma unroll
    for (int r = 0; r < 4; ++r) {
      float l = l_part[mt][r];
      l += __shfl_xor(l, 1, 16);
      l += __shfl_xor(l, 2, 16);
      l += __shfl_xor(l, 4, 16);
      l += __shfl_xor(l, 8, 16);
      inv[mt][r] = 1.0f / l;
    }
#pragma unroll
  for (int mt = 0; mt < 2; ++mt)
#pragma unroll
    for (int nd = 0; nd < 8; ++nd)
#pragma unroll
      for (int r = 0; r < 4; ++r)
        Og[(size_t)(q0w + mt * 16 + quad * 4 + r) * 128 + nd * 16 + l15] =
            f2bf(acc[mt][nd][r] * inv[mt][r]);
}

// ---------------- launcher ----------------
extern "C" void kernel_launch(void* const* d_in, const int* in_sizes, int n_in,
                              void* d_out, int out_size, void* d_ws, size_t ws_size,
                              hipStream_t stream) {
  const float* X    = (const float*)d_in[0];
  const int*   mask = (const int*)d_in[1];
  const float* W_q  = (const float*)d_in[2];
  const float* W_k  = (const float*)d_in[3];
  const float* W_v  = (const float*)d_in[4];
  const float* W_qm = (const float*)d_in[5];
  const float* W_km = (const float*)d_in[6];
  const float* W_vm = (const float*)d_in[7];
  const float* W_o  = (const float*)d_in[8];
  float* out = (float*)d_out;

  char* ws = (char*)d_ws;
  const size_t MB = 1ull << 20;
  u16* Xb    = (u16*)(ws);                 // 16 MB
  u16* Wc0   = (u16*)(ws + 16 * MB);       // 8 MB each
  u16* Wc1   = (u16*)(ws + 24 * MB);
  u16* Wc2   = (u16*)(ws + 32 * MB);
  u16* WmT0  = (u16*)(ws + 40 * MB);
  u16* WmT1  = (u16*)(ws + 48 * MB);
  u16* WmT2  = (u16*)(ws + 56 * MB);
  u16* WqqT0 = (u16*)(ws + 64 * MB);
  u16* WqqT1 = (u16*)(ws + 72 * MB);
  u16* WqqT2 = (u16*)(ws + 80 * MB);
  u16* Qm    = (u16*)(ws + 88 * MB);       // 16 MB each
  u16* Km    = (u16*)(ws + 104 * MB);
  u16* Vm    = (u16*)(ws + 120 * MB);
  u16* VT    = Wc0;    // reuse: Wc dead after weight GEMM
  u16* AO    = WmT0;   // reuse: WmT dead after weight GEMM
  u16* WoT   = WqqT0;  // reuse: WqqT dead after main GEMM

  // casts / transposes
  cast_f32_bf16_x4<<<dim3(8192), dim3(256), 0, stream>>>(X, Xb, 2097152);
  {
    CPtrs c{{W_q, W_k, W_v}, {Wc0, Wc1, Wc2}};
    cast3_w<<<dim3(4096, 1, 3), dim3(256), 0, stream>>>(c, 1048576);
  }
  {
    TPtrs t{{W_qm, W_km, W_vm}, {WmT0, WmT1, WmT2}};
    transpose_cast_w<<<dim3(64, 64, 3), dim3(32, 8), 0, stream>>>(t);
  }

  // fused weights: WqqT[n][k] = (W_q @ W_qm)^T = WmT . Wc^T   (2048^3, z=3)
  {
    GemmArgs g{{WmT0, WmT1, WmT2}, {Wc0, Wc1, Wc2}, {WqqT0, WqqT1, WqqT2}};
    gemm_bt<false><<<dim3(16, 16, 3), dim3(256), 0, stream>>>(g, 2048, 2048, 2048);
  }

  // {Qm,Km,Vm} = Xb . WqqT^T   (4096x2048x2048, z=3)
  {
    GemmArgs g{{Xb, Xb, Xb}, {WqqT0, WqqT1, WqqT2}, {Qm, Km, Vm}};
    gemm_bt<false><<<dim3(16, 32, 3), dim3(256), 0, stream>>>(g, 4096, 2048, 2048);
  }

  transpose_slab<<<dim3(64, 4, 32), dim3(32, 8), 0, stream>>>(Vm, VT);

  flash_attn<<<dim3(16, 16, 2), dim3(256), 0, stream>>>(Qm, Km, VT, mask, AO);

  {
    TPtrs t{{W_o, W_o, W_o}, {WoT, WoT, WoT}};
    transpose_cast_w<<<dim3(64, 64, 1), dim3(32, 8), 0, stream>>>(t);
  }
  {
    GemmArgs g{{AO, AO, AO}, {WoT, WoT, WoT}, {out, out, out}};
    gemm_bt<true><<<dim3(16, 32, 1), dim3(256), 0, stream>>>(g, 4096, 2048, 2048);
  }
}

// Round 5
// 722.742 us; speedup vs baseline: 1.3848x; 1.3848x over previous
//
#include <hip/hip_runtime.h>
#include <hip/hip_bf16.h>

typedef __bf16 bf16x8 __attribute__((ext_vector_type(8)));
typedef float f32x4 __attribute__((ext_vector_type(4)));
typedef unsigned short u16;

__device__ __forceinline__ u16 f2bf(float f) {
  __bf16 b = (__bf16)f;                 // RNE fptrunc
  return __builtin_bit_cast(u16, b);
}
__device__ __forceinline__ float bf2f(u16 v) {
  unsigned int u = ((unsigned int)v) << 16;
  return __builtin_bit_cast(float, u);
}

// ---------------- fused prep: X cast + W_{q,k,v} cast + W_{qm,km,vm} transpose ----------
// flat grid of 256-thread blocks:
//   [0, 8192)      : X cast, 1 float4/thread (2,097,152 float4s)
//   [8192, 20480)  : W cast z = (blk-8192)/4096
//   [20480, 32768) : Wm transpose z = (blk-20480)/4096, 32x32 tiles
struct PrepArgs {
  const float* X; u16* Xb;
  const float* Wsrc[3]; u16* Wdst[3];
  const float* Tsrc[3]; u16* Tdst[3];
};

__global__ void prep(PrepArgs a) {
  __shared__ float t[32][33];
  const int blk = blockIdx.x, tid = threadIdx.x;
  if (blk < 8192) {
    int i = blk * 256 + tid;
    float4 f = reinterpret_cast<const float4*>(a.X)[i];
    ushort4 o;
    o.x = f2bf(f.x); o.y = f2bf(f.y); o.z = f2bf(f.z); o.w = f2bf(f.w);
    reinterpret_cast<ushort4*>(a.Xb)[i] = o;
  } else if (blk < 20480) {
    int r = blk - 8192;
    int z = r >> 12;
    int i = (r & 4095) * 256 + tid;
    float4 f = reinterpret_cast<const float4*>(a.Wsrc[z])[i];
    ushort4 o;
    o.x = f2bf(f.x); o.y = f2bf(f.y); o.z = f2bf(f.z); o.w = f2bf(f.w);
    reinterpret_cast<ushort4*>(a.Wdst[z])[i] = o;
  } else {
    int r = blk - 20480;
    int z = r >> 12;
    int rem = r & 4095;
    int bx = rem & 63, by = rem >> 6;
    const float* src = a.Tsrc[z];
    u16* dst = a.Tdst[z];
    int tx = tid & 31, ty = tid >> 5;
#pragma unroll
    for (int i = 0; i < 4; ++i)
      t[ty + i * 8][tx] = src[(size_t)(by * 32 + ty + i * 8) * 2048 + bx * 32 + tx];
    __syncthreads();
#pragma unroll
    for (int i = 0; i < 4; ++i)
      dst[(size_t)(bx * 32 + ty + i * 8) * 2048 + by * 32 + tx] = f2bf(t[tx][ty + i * 8]);
  }
}

// ---------------- fused post-transpose: Vm slab transpose + W_o transpose+cast ----------
// flat grid: [0,8192) slab transpose (slab=blk>>8), [8192,12288) Wo transpose.
__global__ void post_transpose(const u16* __restrict__ Vm, u16* __restrict__ VT,
                               const float* __restrict__ Wo, u16* __restrict__ WoT) {
  __shared__ u16 ts[32][33];
  __shared__ float tf[32][33];
  const int blk = blockIdx.x, tid = threadIdx.x;
  const int tx = tid & 31, ty = tid >> 5;
  if (blk < 8192) {
    int slab = blk >> 8;
    int rem = blk & 255;
    int bx = rem & 63, by = rem >> 6;          // bx: s-tile (64), by: d-tile (4)
    const u16* s = Vm + (size_t)slab * 2048 * 128;
    u16* d = VT + (size_t)slab * 128 * 2048;
#pragma unroll
    for (int i = 0; i < 4; ++i)
      ts[ty + i * 8][tx] = s[(size_t)(bx * 32 + ty + i * 8) * 128 + by * 32 + tx];
    __syncthreads();
#pragma unroll
    for (int i = 0; i < 4; ++i)
      d[(size_t)(by * 32 + ty + i * 8) * 2048 + bx * 32 + tx] = ts[tx][ty + i * 8];
  } else {
    int rem = blk - 8192;
    int bx = rem & 63, by = rem >> 6;
#pragma unroll
    for (int i = 0; i < 4; ++i)
      tf[ty + i * 8][tx] = Wo[(size_t)(by * 32 + ty + i * 8) * 2048 + bx * 32 + tx];
    __syncthreads();
#pragma unroll
    for (int i = 0; i < 4; ++i)
      WoT[(size_t)(bx * 32 + ty + i * 8) * 2048 + by * 32 + tx] = f2bf(tf[tx][ty + i * 8]);
  }
}

// ---------------- bf16 MFMA GEMM: C[M][N] = A[M][K] * Bt[N][K]^T ----------------
struct GemmArgs { const u16* A[3]; const u16* B[3]; void* C[3]; };

template <bool F32OUT>
__global__ __launch_bounds__(256, 2)
void gemm_bt(GemmArgs g, int M, int N, int K) {
  (void)M;
  __shared__ __align__(16) u16 lds[16384];      // 32 KB: A tile then B tile
  u16* As = lds;
  u16* Bs = lds + 8192;
  const u16* A = g.A[blockIdx.z];
  const u16* B = g.B[blockIdx.z];
  const int tid = threadIdx.x;
  const int lane = tid & 63, w = tid >> 6;
  const int l15 = lane & 15, quad = lane >> 4;
  const int wm = w & 1, wn = w >> 1;
  const int m0 = blockIdx.y * 128, n0 = blockIdx.x * 128;

  const f32x4 zf = {0.f, 0.f, 0.f, 0.f};
  f32x4 acc[4][4];
#pragma unroll
  for (int i = 0; i < 4; ++i)
#pragma unroll
    for (int j = 0; j < 4; ++j) acc[i][j] = zf;

  for (int k0 = 0; k0 < K; k0 += 64) {
#pragma unroll
    for (int t = 0; t < 8; ++t) {
      int idx = w * 8 + t;              // 0..31
      int mat = idx >> 4;               // 0 = A, 1 = B
      int sub = idx & 15;
      int kb = sub >> 1, rb = sub & 1;
      const u16* src = mat ? B : A;
      int row = (mat ? n0 : m0) + rb * 64 + lane;
      const u16* gp = src + (size_t)row * K + k0 + kb * 8;
      u16* lp = (mat ? Bs : As) + (kb * 2 + rb) * 64 * 8;
      __builtin_amdgcn_global_load_lds((const __attribute__((address_space(1))) void*)gp,
                                       (__attribute__((address_space(3))) void*)lp,
                                       16, 0, 0);
    }
    __syncthreads();
#pragma unroll
    for (int kc = 0; kc < 2; ++kc) {
      bf16x8 a[4], bb[4];
#pragma unroll
      for (int mt = 0; mt < 4; ++mt)
        a[mt] = *reinterpret_cast<const bf16x8*>(
            As + (((kc * 4 + quad) * 2 + wm) * 64 + mt * 16 + l15) * 8);
#pragma unroll
      for (int nt = 0; nt < 4; ++nt)
        bb[nt] = *reinterpret_cast<const bf16x8*>(
            Bs + (((kc * 4 + quad) * 2 + wn) * 64 + nt * 16 + l15) * 8);
#pragma unroll
      for (int mt = 0; mt < 4; ++mt)
#pragma unroll
        for (int nt = 0; nt < 4; ++nt)
          acc[mt][nt] = __builtin_amdgcn_mfma_f32_16x16x32_bf16(a[mt], bb[nt], acc[mt][nt], 0, 0, 0);
    }
    __syncthreads();
  }

#pragma unroll
  for (int mt = 0; mt < 4; ++mt)
#pragma unroll
    for (int nt = 0; nt < 4; ++nt)
#pragma unroll
      for (int r = 0; r < 4; ++r) {
        int mrow = m0 + wm * 64 + mt * 16 + quad * 4 + r;   // D row = quad*4+reg
        int ncol = n0 + wn * 64 + nt * 16 + l15;            // D col = lane&15
        if constexpr (F32OUT)
          ((float*)g.C[blockIdx.z])[(size_t)mrow * N + ncol] = acc[mt][nt][r];
        else
          ((u16*)g.C[blockIdx.z])[(size_t)mrow * N + ncol] = f2bf(acc[mt][nt][r]);
      }
}

// ---------------- flash attention (R2 version): no-max softmax, KC=64, 32q/wave -------
// grid (16 qblocks, 16 heads, 2 batch), block 256 (4 waves x 32 q-rows = 128 q/block).
__global__ __launch_bounds__(256, 2)
void flash_attn(const u16* __restrict__ Qm, const u16* __restrict__ Km,
                const u16* __restrict__ VTr, const int* __restrict__ mask,
                u16* __restrict__ Out) {
  __shared__ __align__(16) u16 Ks[16 * 64 * 8];   // [dchunk(16)][kk(64)][8]  16 KB
  __shared__ __align__(16) u16 Vs[8 * 128 * 8];   // [kchunk(8)][d(128)][8]   16 KB
  __shared__ __align__(16) u16 PL[4][32 * 64];    // per-wave P 32x64, XOR-swizzled 16B chunks
  __shared__ u16 Mf[2048];                        // bf16 k-mask multiplier {0,1}

  const int b = blockIdx.z, head = blockIdx.y, qb = blockIdx.x;
  const int slab = b * 16 + head;
  const u16* Qs = Qm + (size_t)slab * 2048 * 128;
  const u16* Kg = Km + (size_t)slab * 2048 * 128;
  const u16* Vg = VTr + (size_t)slab * 128 * 2048;
  u16* Og = Out + (size_t)slab * 2048 * 128;
  const int* mb = mask + b * 2048;

  const int tid = threadIdx.x;
  const int lane = tid & 63, w = tid >> 6;
  const int l15 = lane & 15, quad = lane >> 4;
  const int q0w = qb * 128 + w * 32;

  // stage bf16 k-mask into LDS (once)
#pragma unroll
  for (int j = 0; j < 8; ++j) {
    int i = j * 256 + tid;
    Mf[i] = mb[i] ? (u16)0x3F80 : (u16)0;
  }

  // Q fragments for 2 m-tiles: A[m=lane&15][k=quad*8+j]
  bf16x8 aQ[2][4];
#pragma unroll
  for (int mt = 0; mt < 2; ++mt)
#pragma unroll
    for (int c = 0; c < 4; ++c)
      aQ[mt][c] = *reinterpret_cast<const bf16x8*>(
          Qs + (size_t)(q0w + mt * 16 + l15) * 128 + c * 32 + quad * 8);

  int mq[2][4];
#pragma unroll
  for (int mt = 0; mt < 2; ++mt)
#pragma unroll
    for (int r = 0; r < 4; ++r) mq[mt][r] = mb[q0w + mt * 16 + quad * 4 + r];

  const f32x4 zf = {0.f, 0.f, 0.f, 0.f};
  float l_part[2][4];
  f32x4 acc[2][8];
#pragma unroll
  for (int mt = 0; mt < 2; ++mt) {
#pragma unroll
    for (int r = 0; r < 4; ++r) l_part[mt][r] = 0.f;
#pragma unroll
    for (int nd = 0; nd < 8; ++nd) acc[mt][nd] = zf;
  }

  __syncthreads();   // Mf ready

  u16* PLw = PL[w];

  for (int k0 = 0; k0 < 2048; k0 += 64) {
    // stage K chunk [64 kk][128 d] and VT chunk [128 d][64 kk] via direct-to-LDS
#pragma unroll
    for (int t = 0; t < 8; ++t) {
      int idx = w * 8 + t;              // 0..31
      if (idx < 16) {                   // K: dchunk = idx
        const u16* gp = Kg + (size_t)(k0 + lane) * 128 + idx * 8;
        u16* lp = Ks + idx * 64 * 8;
        __builtin_amdgcn_global_load_lds((const __attribute__((address_space(1))) void*)gp,
                                         (__attribute__((address_space(3))) void*)lp,
                                         16, 0, 0);
      } else {                          // V: kchunk = (idx-16)>>1, d-half = (idx-16)&1
        int u = idx - 16, kc = u >> 1, dh = u & 1;
        const u16* gp = Vg + (size_t)(dh * 64 + lane) * 2048 + k0 + kc * 8;
        u16* lp = Vs + (kc * 128 + dh * 64) * 8;
        __builtin_amdgcn_global_load_lds((const __attribute__((address_space(1))) void*)gp,
                                         (__attribute__((address_space(3))) void*)lp,
                                         16, 0, 0);
      }
    }
    __syncthreads();

    // S[32q x 64k] = Q . K^T
    f32x4 st[2][4];
#pragma unroll
    for (int mt = 0; mt < 2; ++mt)
#pragma unroll
      for (int nt = 0; nt < 4; ++nt) st[mt][nt] = zf;
#pragma unroll
    for (int c = 0; c < 4; ++c)
#pragma unroll
      for (int nt = 0; nt < 4; ++nt) {
        bf16x8 bK = *reinterpret_cast<const bf16x8*>(
            &Ks[((c * 4 + quad) * 64 + nt * 16 + l15) * 8]);
        st[0][nt] = __builtin_amdgcn_mfma_f32_16x16x32_bf16(aQ[0][c], bK, st[0][nt], 0, 0, 0);
        st[1][nt] = __builtin_amdgcn_mfma_f32_16x16x32_bf16(aQ[1][c], bK, st[1][nt], 0, 0, 0);
      }

    // no-max softmax: p = mq ? exp(s)*mk : 1   (exact vs reference semantics)
    float mkf[4];
#pragma unroll
    for (int nt = 0; nt < 4; ++nt) mkf[nt] = bf2f(Mf[k0 + nt * 16 + l15]);

#pragma unroll
    for (int mt = 0; mt < 2; ++mt)
#pragma unroll
      for (int nt = 0; nt < 4; ++nt)
#pragma unroll
        for (int r = 0; r < 4; ++r) {
          float e = __expf(st[mt][nt][r]) * mkf[nt];
          float p = mq[mt][r] ? e : 1.0f;
          l_part[mt][r] += p;
          int row = mt * 16 + quad * 4 + r;            // D row = quad*4+reg
          int col = nt * 16 + l15;                     // D col = lane&15
          int addr = row * 64 + (((col >> 3) ^ (row & 7)) << 3) + (col & 7);
          PLw[addr] = f2bf(p);
        }

    // O += P . V   (VT as B^T; per-wave LDS round trip for P, no barrier needed)
#pragma unroll
    for (int pc = 0; pc < 2; ++pc) {
      bf16x8 aP0 = *reinterpret_cast<const bf16x8*>(
          &PLw[(0 + l15) * 64 + (((pc * 4 + quad) ^ (l15 & 7)) << 3)]);
      bf16x8 aP1 = *reinterpret_cast<const bf16x8*>(
          &PLw[(16 + l15) * 64 + (((pc * 4 + quad) ^ (l15 & 7)) << 3)]);
#pragma unroll
      for (int nd = 0; nd < 8; ++nd) {
        bf16x8 bV = *reinterpret_cast<const bf16x8*>(
            &Vs[((pc * 4 + quad) * 128 + nd * 16 + l15) * 8]);
        acc[0][nd] = __builtin_amdgcn_mfma_f32_16x16x32_bf16(aP0, bV, acc[0][nd], 0, 0, 0);
        acc[1][nd] = __builtin_amdgcn_mfma_f32_16x16x32_bf16(aP1, bV, acc[1][nd], 0, 0, 0);
      }
    }
    __syncthreads();
  }

  // final row-sum reduce over lane&15 (once), then normalize + store
  float inv[2][4];
#pragma unroll
  for (int mt = 0; mt < 2; ++mt)
#pragma unroll
    for (int r = 0; r < 4; ++r) {
      float l = l_part[mt][r];
      l += __shfl_xor(l, 1, 16);
      l += __shfl_xor(l, 2, 16);
      l += __shfl_xor(l, 4, 16);
      l += __shfl_xor(l, 8, 16);
      inv[mt][r] = 1.0f / l;
    }
#pragma unroll
  for (int mt = 0; mt < 2; ++mt)
#pragma unroll
    for (int nd = 0; nd < 8; ++nd)
#pragma unroll
      for (int r = 0; r < 4; ++r)
        Og[(size_t)(q0w + mt * 16 + quad * 4 + r) * 128 + nd * 16 + l15] =
            f2bf(acc[mt][nd][r] * inv[mt][r]);
}

// ---------------- launcher ----------------
extern "C" void kernel_launch(void* const* d_in, const int* in_sizes, int n_in,
                              void* d_out, int out_size, void* d_ws, size_t ws_size,
                              hipStream_t stream) {
  const float* X    = (const float*)d_in[0];
  const int*   mask = (const int*)d_in[1];
  const float* W_q  = (const float*)d_in[2];
  const float* W_k  = (const float*)d_in[3];
  const float* W_v  = (const float*)d_in[4];
  const float* W_qm = (const float*)d_in[5];
  const float* W_km = (const float*)d_in[6];
  const float* W_vm = (const float*)d_in[7];
  const float* W_o  = (const float*)d_in[8];
  float* out = (float*)d_out;

  char* ws = (char*)d_ws;
  const size_t MB = 1ull << 20;
  u16* Xb    = (u16*)(ws);                 // 16 MB
  u16* Wc0   = (u16*)(ws + 16 * MB);       // 8 MB each
  u16* Wc1   = (u16*)(ws + 24 * MB);
  u16* Wc2   = (u16*)(ws + 32 * MB);
  u16* WmT0  = (u16*)(ws + 40 * MB);
  u16* WmT1  = (u16*)(ws + 48 * MB);
  u16* WmT2  = (u16*)(ws + 56 * MB);
  u16* WqqT0 = (u16*)(ws + 64 * MB);
  u16* WqqT1 = (u16*)(ws + 72 * MB);
  u16* WqqT2 = (u16*)(ws + 80 * MB);
  u16* Qm    = (u16*)(ws + 88 * MB);       // 16 MB each
  u16* Km    = (u16*)(ws + 104 * MB);
  u16* Vm    = (u16*)(ws + 120 * MB);
  u16* VT    = Wc0;    // reuse: Wc dead after weight GEMM
  u16* AO    = WmT0;   // reuse: WmT dead after weight GEMM
  u16* WoT   = WqqT0;  // reuse: WqqT dead after main GEMM

  // fused prep: X cast, W_{q,k,v} cast, W_{qm,km,vm} transpose
  {
    PrepArgs a;
    a.X = X; a.Xb = Xb;
    a.Wsrc[0] = W_q;  a.Wsrc[1] = W_k;  a.Wsrc[2] = W_v;
    a.Wdst[0] = Wc0;  a.Wdst[1] = Wc1;  a.Wdst[2] = Wc2;
    a.Tsrc[0] = W_qm; a.Tsrc[1] = W_km; a.Tsrc[2] = W_vm;
    a.Tdst[0] = WmT0; a.Tdst[1] = WmT1; a.Tdst[2] = WmT2;
    prep<<<dim3(32768), dim3(256), 0, stream>>>(a);
  }

  // fused weights: WqqT[n][k] = (W_q @ W_qm)^T = WmT . Wc^T   (2048^3, z=3)
  {
    GemmArgs g{{WmT0, WmT1, WmT2}, {Wc0, Wc1, Wc2}, {WqqT0, WqqT1, WqqT2}};
    gemm_bt<false><<<dim3(16, 16, 3), dim3(256), 0, stream>>>(g, 2048, 2048, 2048);
  }

  // {Qm,Km,Vm} = Xb . WqqT^T   (4096x2048x2048, z=3)
  {
    GemmArgs g{{Xb, Xb, Xb}, {WqqT0, WqqT1, WqqT2}, {Qm, Km, Vm}};
    gemm_bt<false><<<dim3(16, 32, 3), dim3(256), 0, stream>>>(g, 4096, 2048, 2048);
  }

  // fused: Vm slab transpose -> VT, W_o transpose -> WoT
  post_transpose<<<dim3(12288), dim3(256), 0, stream>>>(Vm, VT, W_o, WoT);

  flash_attn<<<dim3(16, 16, 2), dim3(256), 0, stream>>>(Qm, Km, VT, mask, AO);

  {
    GemmArgs g{{AO, AO, AO}, {WoT, WoT, WoT}, {out, out, out}};
    gemm_bt<true><<<dim3(16, 32, 1), dim3(256), 0, stream>>>(g, 4096, 2048, 2048);
  }
}